// Round 7
// baseline (261.401 us; speedup 1.0000x reference)
//
#include <hip/hip_runtime.h>
#include <hip/hip_bf16.h>

// Problem constants (static per reference)
#define D 128
#define H 64
#define R 4
#define NT 64      // nodes per tile/block
#define LDC 132    // LDS stride for 128-wide chunks (16B-aligned rows, bank stagger)
#define LDH 68     // LDS stride for 64-wide hidden

// MFMA fragment types
typedef __attribute__((ext_vector_type(8))) short bf16x8;
typedef __attribute__((ext_vector_type(4))) float f32x4;

// Weight-prep layout: per relation, 56 frags of 512 bf16 elems (64 lanes x 8):
//   W1 frags [0,16), W2 [16,24), W3 [24,40), Wu1_{r+1} [40,56)
// Updater block appended at UBASE: Wu1[0:128] [0,16), Wu2 [16,24), Wu3 [24,40)
// Frag f = ntile*KSTEPS + kstep; lane l covers col = ntile*16+(l&15),
// k = kstep*32 + (l>>4)*8 + i.  (Same phi used for A -> phi cancels.)
#define PREL 56
#define PFRAG 512
#define UBASE (R * PREL)     // 224
#define UPREL 40
#define NFRAG (UBASE + UPREL)

__device__ __forceinline__ float4 relu4(float4 v) {
    return make_float4(fmaxf(v.x, 0.f), fmaxf(v.y, 0.f), fmaxf(v.z, 0.f), fmaxf(v.w, 0.f));
}

// split fp32 -> bf16 hi (RTZ) + bf16 lo (residual, RTZ)
__device__ __forceinline__ void split1(float x, short& hi, short& lo) {
    unsigned u = __float_as_uint(x);
    unsigned hb = u & 0xffff0000u;
    float res = x - __uint_as_float(hb);
    hi = (short)(u >> 16);
    lo = (short)(__float_as_uint(res) >> 16);
}

__device__ __forceinline__ void split8(const float* x8, bf16x8& hi, bf16x8& lo) {
#pragma unroll
    for (int i = 0; i < 8; ++i) {
        short h, l;
        split1(x8[i], h, l);
        hi[i] = h; lo[i] = l;
    }
}

// One 16-row output strip: acc[NT_TILES] of 16x16 tiles, A from LDS fp32, B pre-split global.
template<int NT_TILES, int KSTEPS>
__device__ __forceinline__ void mfma_layer(const float* Als, int ld,
                                           const short* __restrict__ Bhi,
                                           const short* __restrict__ Blo,
                                           int lane, f32x4* acc) {
#pragma unroll
    for (int ks = 0; ks < KSTEPS; ++ks) {
        const float* ap = Als + (lane & 15) * ld + ks * 32 + ((lane >> 4) << 3);
        float x8[8];
        *(float4*)&x8[0] = *(const float4*)ap;
        *(float4*)&x8[4] = *(const float4*)(ap + 4);
        bf16x8 ah, al;
        split8(x8, ah, al);
#pragma unroll
        for (int n = 0; n < NT_TILES; ++n) {
            int f = n * KSTEPS + ks;
            bf16x8 bh = *(const bf16x8*)(Bhi + (((size_t)f * 64 + lane) << 3));
            bf16x8 bl = *(const bf16x8*)(Blo + (((size_t)f * 64 + lane) << 3));
            acc[n] = __builtin_amdgcn_mfma_f32_16x16x32_bf16(ah, bh, acc[n], 0, 0, 0);
            acc[n] = __builtin_amdgcn_mfma_f32_16x16x32_bf16(ah, bl, acc[n], 0, 0, 0);
            acc[n] = __builtin_amdgcn_mfma_f32_16x16x32_bf16(al, bh, acc[n], 0, 0, 0);
        }
    }
}

// bias + relu + store C strip to LDS fp32 (C/D layout: col=lane&15, row=(lane>>4)*4+reg)
template<int NT_TILES>
__device__ __forceinline__ void store_C_lds(const f32x4* acc, const float* __restrict__ bias,
                                            float* Ld, int ld, int lane) {
    int r0 = (lane >> 4) << 2;
#pragma unroll
    for (int n = 0; n < NT_TILES; ++n) {
        int col = n * 16 + (lane & 15);
        float bv = bias[col];
#pragma unroll
        for (int q = 0; q < 4; ++q)
            Ld[(r0 + q) * ld + col] = fmaxf(acc[n][q] + bv, 0.f);
    }
}

// ---------------- CSR build ----------------

__global__ __launch_bounds__(256) void k_count(const int* __restrict__ dst, int* __restrict__ cnt, int E) {
    int e = blockIdx.x * 256 + threadIdx.x;
    if (e < E) atomicAdd(&cnt[dst[e]], 1);
}

// phase 1: per-256-chunk sums
__global__ __launch_bounds__(256) void k_blocksum(const int* __restrict__ cnt,
                                                  int* __restrict__ bsum, int N) {
    __shared__ int red[256];
    int i = blockIdx.x * 256 + threadIdx.x;
    red[threadIdx.x] = (i < N) ? cnt[i] : 0;
    __syncthreads();
    for (int off = 128; off > 0; off >>= 1) {
        if (threadIdx.x < off) red[threadIdx.x] += red[threadIdx.x + off];
        __syncthreads();
    }
    if (threadIdx.x == 0) bsum[blockIdx.x] = red[0];
}

// phase 2: exclusive scan of up-to-1024 block sums (single block)
__global__ __launch_bounds__(1024) void k_scan_bsums(int* __restrict__ bsum, int G) {
    __shared__ int s[1024];
    int t = threadIdx.x;
    int v = (t < G) ? bsum[t] : 0;
    s[t] = v;
    __syncthreads();
    for (int off = 1; off < 1024; off <<= 1) {
        int u = (t >= off) ? s[t - off] : 0;
        __syncthreads();
        s[t] += u;
        __syncthreads();
    }
    if (t < G) bsum[t] = s[t] - v;   // exclusive
}

// phase 3: in-block prefix + block offset -> offs, cursor
__global__ __launch_bounds__(256) void k_scan_offs(const int* __restrict__ cnt,
                                                   const int* __restrict__ bsum,
                                                   int* __restrict__ offs,
                                                   int* __restrict__ cursor, int N) {
    __shared__ int s[256];
    int t = threadIdx.x;
    int i = blockIdx.x * 256 + t;
    int v = (i < N) ? cnt[i] : 0;
    s[t] = v;
    __syncthreads();
    for (int off = 1; off < 256; off <<= 1) {
        int u = (t >= off) ? s[t - off] : 0;
        __syncthreads();
        s[t] += u;
        __syncthreads();
    }
    if (i < N) {
        int e = s[t] - v + bsum[blockIdx.x];
        offs[i] = e;
        cursor[i] = e;
    }
}

__global__ __launch_bounds__(256) void k_fill(const int* __restrict__ src, const int* __restrict__ dst,
                                              const int* __restrict__ etype, int* __restrict__ cursor,
                                              int* __restrict__ eidx, int E) {
    int e = blockIdx.x * 256 + threadIdx.x;
    if (e < E) {
        int d = dst[e];
        int p = atomicAdd(&cursor[d], 1);
        eidx[p] = src[e] * 4 + etype[e];
    }
}

// ---------------- Weight prep: split + frag-swizzle all B matrices ----------------

__global__ __launch_bounds__(256) void k_wprep(
    const float* __restrict__ W1, const float* __restrict__ W2,
    const float* __restrict__ W3, const float* __restrict__ Wu1,
    const float* __restrict__ Wu2, const float* __restrict__ Wu3,
    short* __restrict__ Phi, short* __restrict__ Plo)
{
    int pair = blockIdx.x;
    const float* src; int KS, NTl, fragbase, ncol;
    if (pair < 16) {
        int r = pair >> 2, mat = pair & 3;
        if (mat == 0)      { src = W1  + (size_t)r * (D * H);       KS = 4; NTl = 4; fragbase = r * PREL + 0;  ncol = 64;  }
        else if (mat == 1) { src = W2  + (size_t)r * (H * H);       KS = 2; NTl = 4; fragbase = r * PREL + 16; ncol = 64;  }
        else if (mat == 2) { src = W3  + (size_t)r * (H * D);       KS = 2; NTl = 8; fragbase = r * PREL + 24; ncol = 128; }
        else               { src = Wu1 + (size_t)(r + 1) * D * H;   KS = 4; NTl = 4; fragbase = r * PREL + 40; ncol = 64;  }
    } else {
        int mat = pair - 16;
        if (mat == 0)      { src = Wu1; KS = 4; NTl = 4; fragbase = UBASE + 0;  ncol = 64;  }  // rows 0..127
        else if (mat == 1) { src = Wu2; KS = 2; NTl = 4; fragbase = UBASE + 16; ncol = 64;  }
        else               { src = Wu3; KS = 2; NTl = 8; fragbase = UBASE + 24; ncol = 128; }
    }
    int nf = NTl * KS;
    for (int u = threadIdx.x; u < nf * 64; u += 256) {
        int f = u >> 6, lane = u & 63;
        int n = f / KS, ks = f - n * KS;
        int col = n * 16 + (lane & 15);
        int k0 = ks * 32 + ((lane >> 4) << 3);
        size_t dstp = (((size_t)(fragbase + f)) * 64 + (size_t)lane) * 8;
#pragma unroll
        for (int i = 0; i < 8; ++i) {
            short h, l;
            split1(src[(size_t)(k0 + i) * ncol + col], h, l);
            Phi[dstp + i] = h;
            Plo[dstp + i] = l;
        }
    }
}

// ---------------- Stage A: per-(node, relation) message MLP + Wu1 fold ----------------
// Barrier-free: each wave owns a 16-row strip; all LDS reuse is wave-private and
// flows through registers (acc -> store -> load), so no __syncthreads needed.

__global__ __launch_bounds__(256) void k_mlp_rel(
    const float* __restrict__ X,
    const float* __restrict__ b1, const float* __restrict__ b2, const float* __restrict__ b3,
    const short* __restrict__ Phi, const short* __restrict__ Plo,
    float* __restrict__ U, int N)
{
    __shared__ float Xs[NT * LDC];   // X tile, later T tile (per-wave strips)
    __shared__ float Hs[NT * LDH];   // H1, later H2 (per-wave strips)

    const int tid = threadIdx.x;
    const int lane = tid & 63;
    const int w = tid >> 6;
    const int m16 = w * 16;
    const int r = blockIdx.x & 3;
    const int n0 = (blockIdx.x >> 2) * NT;

    const short* PH = Phi + (size_t)(r * PREL) * PFRAG;
    const short* PL = Plo + (size_t)(r * PREL) * PFRAG;
    const float* b1r = b1 + r * H;
    const float* b2r = b2 + r * H;
    const float* b3r = b3 + r * D;

    // wave-private staging: this wave loads its own 16 rows (16*32 float4 / 64 lanes = 8 each)
    for (int i = lane; i < 16 * 32; i += 64) {
        int row = i >> 5;
        int c4 = (i & 31) << 2;
        int n = n0 + m16 + row;
        float4 v = make_float4(0.f, 0.f, 0.f, 0.f);
        if (n < N) v = *(const float4*)&X[(size_t)n * D + c4];
        *(float4*)&Xs[(m16 + row) * LDC + c4] = v;
    }

    // layer 1: X(16x128) @ W1(128x64)
    f32x4 acc[8];
#pragma unroll
    for (int n = 0; n < 4; ++n) acc[n] = (f32x4){0.f, 0.f, 0.f, 0.f};
    mfma_layer<4, 4>(&Xs[m16 * LDC], LDC, PH, PL, lane, acc);
    store_C_lds<4>(acc, b1r, &Hs[m16 * LDH], LDH, lane);   // H1

    // layer 2: H1(16x64) @ W2(64x64) -> H2 (in place; data flows through regs)
#pragma unroll
    for (int n = 0; n < 4; ++n) acc[n] = (f32x4){0.f, 0.f, 0.f, 0.f};
    mfma_layer<4, 2>(&Hs[m16 * LDH], LDH, PH + (size_t)16 * PFRAG, PL + (size_t)16 * PFRAG, lane, acc);
    store_C_lds<4>(acc, b2r, &Hs[m16 * LDH], LDH, lane);   // H2

    // layer 3: H2(16x64) @ W3(64x128), relu -> T (into Xs strip)
#pragma unroll
    for (int n = 0; n < 8; ++n) acc[n] = (f32x4){0.f, 0.f, 0.f, 0.f};
    mfma_layer<8, 2>(&Hs[m16 * LDH], LDH, PH + (size_t)24 * PFRAG, PL + (size_t)24 * PFRAG, lane, acc);
    store_C_lds<8>(acc, b3r, &Xs[m16 * LDC], LDC, lane);   // T

    // U projection: T(16x128) @ Wu1_{r+1}(128x64)
#pragma unroll
    for (int n = 0; n < 4; ++n) acc[n] = (f32x4){0.f, 0.f, 0.f, 0.f};
    mfma_layer<4, 4>(&Xs[m16 * LDC], LDC, PH + (size_t)40 * PFRAG, PL + (size_t)40 * PFRAG, lane, acc);
    {
        int r0 = (lane >> 4) << 2;
#pragma unroll
        for (int n = 0; n < 4; ++n) {
            int col = n * 16 + (lane & 15);
#pragma unroll
            for (int q = 0; q < 4; ++q) {
                int node = n0 + m16 + r0 + q;
                if (node < N)
                    U[((size_t)node * R + r) * H + col] = acc[n][q];
            }
        }
    }
}

// ---------------- Stage B: gather S[n] = sum over in-edges of U[src*4+rel] ----------------

__global__ __launch_bounds__(256) void k_gather(
    const float* __restrict__ U,
    const int* __restrict__ cnt, const int* __restrict__ offs, const int* __restrict__ eidx,
    float* __restrict__ S, int N)
{
    const int wid = threadIdx.x >> 6, lane = threadIdx.x & 63;
    const int n = blockIdx.x * 4 + wid;
    if (n >= N) return;
    const int g = cnt[n];
    const int s = offs[n];
    float acc = 0.f;
    for (int base = 0; base < g; base += 64) {
        int m = g - base; if (m > 64) m = 64;
        int v = 0;
        if (lane < m) v = eidx[s + base + lane];
        for (int j0 = 0; j0 < m; j0 += 8) {
            int lim = m - j0; if (lim > 8) lim = 8;
            float t[8];
#pragma unroll
            for (int j = 0; j < 8; ++j) {
                int vi = __shfl(v, j0 + j);
                t[j] = (j < lim) ? U[(size_t)vi * H + lane] : 0.f;
            }
#pragma unroll
            for (int j = 0; j < 8; ++j) acc += t[j];
        }
    }
    S[(size_t)n * H + lane] = acc;
}

// ---------------- Stage C: updater MLP + select (split-bf16 MFMA, barrier-free) ----------------

__global__ __launch_bounds__(256) void k_upd(
    const float* __restrict__ X, const float* __restrict__ S,
    const int* __restrict__ cnt, const int* __restrict__ node_type,
    const short* __restrict__ Phi, const short* __restrict__ Plo,
    const float* __restrict__ bu1, const float* __restrict__ bu2, const float* __restrict__ bu3,
    float* __restrict__ out, int N)
{
    __shared__ float Xs[NT * LDC];   // chunk0 tile (per-wave strips)
    __shared__ float Hs[NT * LDH];   // H1 / H2 (per-wave strips)

    const int tid = threadIdx.x;
    const int lane = tid & 63;
    const int w = tid >> 6;
    const int m16 = w * 16;
    const int n0 = blockIdx.x * NT;

    const short* PH = Phi + (size_t)UBASE * PFRAG;
    const short* PL = Plo + (size_t)UBASE * PFRAG;

    // wave-private staging: enc chunk 0 = relu(x) * (indeg > 0) for own 16 rows
    for (int i = lane; i < 16 * 32; i += 64) {
        int row = i >> 5;
        int c4 = (i & 31) << 2;
        int n = n0 + m16 + row;
        float4 v = make_float4(0.f, 0.f, 0.f, 0.f);
        if (n < N && cnt[n] > 0)
            v = relu4(*(const float4*)&X[(size_t)n * D + c4]);
        *(float4*)&Xs[(m16 + row) * LDC + c4] = v;
    }

    // layer 1: chunk0 @ Wu1[0:128] + S + bu1, relu -> H1
    f32x4 acc[8];
#pragma unroll
    for (int n = 0; n < 4; ++n) acc[n] = (f32x4){0.f, 0.f, 0.f, 0.f};
    mfma_layer<4, 4>(&Xs[m16 * LDC], LDC, PH, PL, lane, acc);
    {
        int r0 = (lane >> 4) << 2;
#pragma unroll
        for (int n = 0; n < 4; ++n) {
            int col = n * 16 + (lane & 15);
            float bv = bu1[col];
#pragma unroll
            for (int q = 0; q < 4; ++q) {
                int node = n0 + m16 + r0 + q;
                float sv = (node < N) ? S[(size_t)node * H + col] : 0.f;
                Hs[(m16 + r0 + q) * LDH + col] = fmaxf(acc[n][q] + bv + sv, 0.f);
            }
        }
    }

    // layer 2: H1 @ Wu2, relu -> H2 (in place)
#pragma unroll
    for (int n = 0; n < 4; ++n) acc[n] = (f32x4){0.f, 0.f, 0.f, 0.f};
    mfma_layer<4, 2>(&Hs[m16 * LDH], LDH, PH + (size_t)16 * PFRAG, PL + (size_t)16 * PFRAG, lane, acc);
    store_C_lds<4>(acc, bu2, &Hs[m16 * LDH], LDH, lane);

    // layer 3: H2 @ Wu3 (linear) + select by node_type
#pragma unroll
    for (int n = 0; n < 8; ++n) acc[n] = (f32x4){0.f, 0.f, 0.f, 0.f};
    mfma_layer<8, 2>(&Hs[m16 * LDH], LDH, PH + (size_t)24 * PFRAG, PL + (size_t)24 * PFRAG, lane, acc);
    {
        int r0 = (lane >> 4) << 2;
#pragma unroll
        for (int q = 0; q < 4; ++q) {
            int node = n0 + m16 + r0 + q;
            if (node >= N) continue;
            int t = node_type[node];
#pragma unroll
            for (int n = 0; n < 8; ++n) {
                int col = n * 16 + (lane & 15);
                float o = (t <= 1) ? (acc[n][q] + bu3[col])
                                   : X[(size_t)node * D + col];
                out[(size_t)node * D + col] = o;
            }
        }
    }
}

extern "C" void kernel_launch(void* const* d_in, const int* in_sizes, int n_in,
                              void* d_out, int out_size, void* d_ws, size_t ws_size,
                              hipStream_t stream) {
    const float* X     = (const float*)d_in[0];
    const int*   src   = (const int*)d_in[1];
    const int*   dst   = (const int*)d_in[2];
    const int*   etype = (const int*)d_in[3];
    const int*   ntype = (const int*)d_in[4];
    const float* W1    = (const float*)d_in[5];
    const float* b1    = (const float*)d_in[6];
    const float* W2    = (const float*)d_in[7];
    const float* b2    = (const float*)d_in[8];
    const float* W3    = (const float*)d_in[9];
    const float* b3    = (const float*)d_in[10];
    const float* Wu1   = (const float*)d_in[11];
    const float* bu1   = (const float*)d_in[12];
    const float* Wu2   = (const float*)d_in[13];
    const float* bu2   = (const float*)d_in[14];
    const float* Wu3   = (const float*)d_in[15];
    const float* bu3   = (const float*)d_in[16];
    float* out = (float*)d_out;

    const int N = in_sizes[4];
    const int E = in_sizes[1];

    // workspace layout
    float* U    = (float*)d_ws;                       // N*R*H floats (51.2 MB)
    float* S    = U + (size_t)N * R * H;              // N*H floats (12.8 MB)
    int* cnt    = (int*)(S + (size_t)N * H);          // N
    int* offs   = cnt + N;                            // N
    int* cursor = offs + N;                           // N
    int* eidx   = cursor + N;                         // E
    short* Phi  = (short*)(eidx + E);                 // NFRAG*PFRAG shorts
    short* Plo  = Phi + (size_t)NFRAG * PFRAG;
    int* bsum   = (int*)(Plo + (size_t)NFRAG * PFRAG);  // ceil(N/256)

    hipMemsetAsync(cnt, 0, (size_t)N * sizeof(int), stream);

    int eb = (E + 255) / 256;
    int G = (N + 255) / 256;
    k_count<<<eb, 256, 0, stream>>>(dst, cnt, E);
    k_blocksum<<<G, 256, 0, stream>>>(cnt, bsum, N);
    k_scan_bsums<<<1, 1024, 0, stream>>>(bsum, G);
    k_scan_offs<<<G, 256, 0, stream>>>(cnt, bsum, offs, cursor, N);
    k_fill<<<eb, 256, 0, stream>>>(src, dst, etype, cursor, eidx, E);
    k_wprep<<<19, 256, 0, stream>>>(W1, W2, W3, Wu1, Wu2, Wu3, Phi, Plo);

    int tiles = (N + NT - 1) / NT;
    k_mlp_rel<<<tiles * R, 256, 0, stream>>>(X, b1, b2, b3, Phi, Plo, U, N);
    k_gather<<<(N + 3) / 4, 256, 0, stream>>>(U, cnt, offs, eidx, S, N);
    k_upd<<<tiles, 256, 0, stream>>>(X, S, cnt, ntype, Phi, Plo, bu1, bu2, bu3, out, N);
}

// Round 8
// 251.493 us; speedup vs baseline: 1.0394x; 1.0394x over previous
//
#include <hip/hip_runtime.h>
#include <hip/hip_bf16.h>

// Problem constants (static per reference)
#define D 128
#define H 64
#define R 4
#define NT 64      // nodes per tile/block
#define LDC 132    // LDS stride for 128-wide chunks (16B-aligned rows, bank stagger)
#define LDH 68     // LDS stride for 64-wide hidden

// MFMA fragment types
typedef __attribute__((ext_vector_type(8))) short bf16x8;
typedef __attribute__((ext_vector_type(4))) float f32x4;

// Weight-prep layout: per relation, 56 frags of 512 bf16 elems (64 lanes x 8):
//   W1 frags [0,16), W2 [16,24), W3 [24,40), Wu1_{r+1} [40,56)
// Updater block appended at UBASE: Wu1[0:128] [0,16), Wu2 [16,24), Wu3 [24,40)
// Frag f = ntile*KSTEPS + kstep; lane l covers col = ntile*16+(l&15),
// k = kstep*32 + (l>>4)*8 + i.  (Same phi used for A -> phi cancels.)
#define PREL 56
#define PFRAG 512
#define UBASE (R * PREL)     // 224
#define UPREL 40
#define NFRAG (UBASE + UPREL)

__device__ __forceinline__ float4 relu4(float4 v) {
    return make_float4(fmaxf(v.x, 0.f), fmaxf(v.y, 0.f), fmaxf(v.z, 0.f), fmaxf(v.w, 0.f));
}

// split fp32 -> bf16 hi (RTZ) + bf16 lo (residual, RTZ)
__device__ __forceinline__ void split1(float x, short& hi, short& lo) {
    unsigned u = __float_as_uint(x);
    unsigned hb = u & 0xffff0000u;
    float res = x - __uint_as_float(hb);
    hi = (short)(u >> 16);
    lo = (short)(__float_as_uint(res) >> 16);
}

__device__ __forceinline__ void split8(const float* x8, bf16x8& hi, bf16x8& lo) {
#pragma unroll
    for (int i = 0; i < 8; ++i) {
        short h, l;
        split1(x8[i], h, l);
        hi[i] = h; lo[i] = l;
    }
}

// A from LDS fp32 (split on the fly), B pre-split global.
template<int NT_TILES, int KSTEPS>
__device__ __forceinline__ void mfma_layer(const float* Als, int ld,
                                           const short* __restrict__ Bhi,
                                           const short* __restrict__ Blo,
                                           int lane, f32x4* acc) {
#pragma unroll
    for (int ks = 0; ks < KSTEPS; ++ks) {
        const float* ap = Als + (lane & 15) * ld + ks * 32 + ((lane >> 4) << 3);
        float x8[8];
        *(float4*)&x8[0] = *(const float4*)ap;
        *(float4*)&x8[4] = *(const float4*)(ap + 4);
        bf16x8 ah, al;
        split8(x8, ah, al);
#pragma unroll
        for (int n = 0; n < NT_TILES; ++n) {
            int f = n * KSTEPS + ks;
            bf16x8 bh = *(const bf16x8*)(Bhi + (((size_t)f * 64 + lane) << 3));
            bf16x8 bl = *(const bf16x8*)(Blo + (((size_t)f * 64 + lane) << 3));
            acc[n] = __builtin_amdgcn_mfma_f32_16x16x32_bf16(ah, bh, acc[n], 0, 0, 0);
            acc[n] = __builtin_amdgcn_mfma_f32_16x16x32_bf16(ah, bl, acc[n], 0, 0, 0);
            acc[n] = __builtin_amdgcn_mfma_f32_16x16x32_bf16(al, bh, acc[n], 0, 0, 0);
        }
    }
}

// A from pre-split registers (cached across relations), B pre-split global.
template<int NT_TILES, int KSTEPS>
__device__ __forceinline__ void mfma_layer_regA(const bf16x8* ah, const bf16x8* al,
                                                const short* __restrict__ Bhi,
                                                const short* __restrict__ Blo,
                                                int lane, f32x4* acc) {
#pragma unroll
    for (int ks = 0; ks < KSTEPS; ++ks) {
#pragma unroll
        for (int n = 0; n < NT_TILES; ++n) {
            int f = n * KSTEPS + ks;
            bf16x8 bh = *(const bf16x8*)(Bhi + (((size_t)f * 64 + lane) << 3));
            bf16x8 bl = *(const bf16x8*)(Blo + (((size_t)f * 64 + lane) << 3));
            acc[n] = __builtin_amdgcn_mfma_f32_16x16x32_bf16(ah[ks], bh, acc[n], 0, 0, 0);
            acc[n] = __builtin_amdgcn_mfma_f32_16x16x32_bf16(ah[ks], bl, acc[n], 0, 0, 0);
            acc[n] = __builtin_amdgcn_mfma_f32_16x16x32_bf16(al[ks], bh, acc[n], 0, 0, 0);
        }
    }
}

// bias + relu + store C strip to LDS fp32 (C/D layout: col=lane&15, row=(lane>>4)*4+reg)
template<int NT_TILES>
__device__ __forceinline__ void store_C_lds(const f32x4* acc, const float* __restrict__ bias,
                                            float* Ld, int ld, int lane) {
    int r0 = (lane >> 4) << 2;
#pragma unroll
    for (int n = 0; n < NT_TILES; ++n) {
        int col = n * 16 + (lane & 15);
        float bv = bias[col];
#pragma unroll
        for (int q = 0; q < 4; ++q)
            Ld[(r0 + q) * ld + col] = fmaxf(acc[n][q] + bv, 0.f);
    }
}

// ---------------- CSR build ----------------

__global__ __launch_bounds__(256) void k_count(const int* __restrict__ dst, int* __restrict__ cnt, int E) {
    int e = blockIdx.x * 256 + threadIdx.x;
    if (e < E) atomicAdd(&cnt[dst[e]], 1);
}

__global__ __launch_bounds__(256) void k_blocksum(const int* __restrict__ cnt,
                                                  int* __restrict__ bsum, int N) {
    __shared__ int red[256];
    int i = blockIdx.x * 256 + threadIdx.x;
    red[threadIdx.x] = (i < N) ? cnt[i] : 0;
    __syncthreads();
    for (int off = 128; off > 0; off >>= 1) {
        if (threadIdx.x < off) red[threadIdx.x] += red[threadIdx.x + off];
        __syncthreads();
    }
    if (threadIdx.x == 0) bsum[blockIdx.x] = red[0];
}

__global__ __launch_bounds__(1024) void k_scan_bsums(int* __restrict__ bsum, int G) {
    __shared__ int s[1024];
    int t = threadIdx.x;
    int v = (t < G) ? bsum[t] : 0;
    s[t] = v;
    __syncthreads();
    for (int off = 1; off < 1024; off <<= 1) {
        int u = (t >= off) ? s[t - off] : 0;
        __syncthreads();
        s[t] += u;
        __syncthreads();
    }
    if (t < G) bsum[t] = s[t] - v;   // exclusive
}

__global__ __launch_bounds__(256) void k_scan_offs(const int* __restrict__ cnt,
                                                   const int* __restrict__ bsum,
                                                   int* __restrict__ offs,
                                                   int* __restrict__ cursor, int N) {
    __shared__ int s[256];
    int t = threadIdx.x;
    int i = blockIdx.x * 256 + t;
    int v = (i < N) ? cnt[i] : 0;
    s[t] = v;
    __syncthreads();
    for (int off = 1; off < 256; off <<= 1) {
        int u = (t >= off) ? s[t - off] : 0;
        __syncthreads();
        s[t] += u;
        __syncthreads();
    }
    if (i < N) {
        int e = s[t] - v + bsum[blockIdx.x];
        offs[i] = e;
        cursor[i] = e;
    }
}

__global__ __launch_bounds__(256) void k_fill(const int* __restrict__ src, const int* __restrict__ dst,
                                              const int* __restrict__ etype, int* __restrict__ cursor,
                                              int* __restrict__ eidx, int E) {
    int e = blockIdx.x * 256 + threadIdx.x;
    if (e < E) {
        int d = dst[e];
        int p = atomicAdd(&cursor[d], 1);
        eidx[p] = src[e] * 4 + etype[e];
    }
}

// ---------------- Weight prep: split + frag-swizzle all B matrices ----------------

__global__ __launch_bounds__(256) void k_wprep(
    const float* __restrict__ W1, const float* __restrict__ W2,
    const float* __restrict__ W3, const float* __restrict__ Wu1,
    const float* __restrict__ Wu2, const float* __restrict__ Wu3,
    short* __restrict__ Phi, short* __restrict__ Plo)
{
    int pair = blockIdx.x;
    const float* src; int KS, NTl, fragbase, ncol;
    if (pair < 16) {
        int r = pair >> 2, mat = pair & 3;
        if (mat == 0)      { src = W1  + (size_t)r * (D * H);       KS = 4; NTl = 4; fragbase = r * PREL + 0;  ncol = 64;  }
        else if (mat == 1) { src = W2  + (size_t)r * (H * H);       KS = 2; NTl = 4; fragbase = r * PREL + 16; ncol = 64;  }
        else if (mat == 2) { src = W3  + (size_t)r * (H * D);       KS = 2; NTl = 8; fragbase = r * PREL + 24; ncol = 128; }
        else               { src = Wu1 + (size_t)(r + 1) * D * H;   KS = 4; NTl = 4; fragbase = r * PREL + 40; ncol = 64;  }
    } else {
        int mat = pair - 16;
        if (mat == 0)      { src = Wu1; KS = 4; NTl = 4; fragbase = UBASE + 0;  ncol = 64;  }  // rows 0..127
        else if (mat == 1) { src = Wu2; KS = 2; NTl = 4; fragbase = UBASE + 16; ncol = 64;  }
        else               { src = Wu3; KS = 2; NTl = 8; fragbase = UBASE + 24; ncol = 128; }
    }
    int nf = NTl * KS;
    for (int u = threadIdx.x; u < nf * 64; u += 256) {
        int f = u >> 6, lane = u & 63;
        int n = f / KS, ks = f - n * KS;
        int col = n * 16 + (lane & 15);
        int k0 = ks * 32 + ((lane >> 4) << 3);
        size_t dstp = (((size_t)(fragbase + f)) * 64 + (size_t)lane) * 8;
#pragma unroll
        for (int i = 0; i < 8; ++i) {
            short h, l;
            split1(src[(size_t)(k0 + i) * ncol + col], h, l);
            Phi[dstp + i] = h;
            Plo[dstp + i] = l;
        }
    }
}

// ---------------- Stage A: fused 4-relation message MLP + Wu1 fold ----------------
// One block per 64-node tile; each wave owns 16 rows and loops r=0..3 with the
// X A-fragments split once and cached in registers. Wave-private LDS strips,
// barrier-free.

__global__ __launch_bounds__(256) void k_mlp_rel(
    const float* __restrict__ X,
    const float* __restrict__ b1, const float* __restrict__ b2, const float* __restrict__ b3,
    const short* __restrict__ Phi, const short* __restrict__ Plo,
    float* __restrict__ U, int N)
{
    __shared__ float Ts[NT * LDC];   // T strips (per wave)
    __shared__ float Hs[NT * LDH];   // H1/H2 strips (per wave)

    const int tid = threadIdx.x;
    const int lane = tid & 63;
    const int w = tid >> 6;
    const int m16 = w * 16;
    const int n0 = blockIdx.x * NT;

    // stage X A-fragments direct from global into registers, split once
    bf16x8 ahx[4], alx[4];
    {
        int row = n0 + m16 + (lane & 15);
        const float* xp = X + (size_t)row * D + ((lane >> 4) << 3);
        bool ok = (row < N);
#pragma unroll
        for (int ks = 0; ks < 4; ++ks) {
            float x8[8];
            if (ok) {
                *(float4*)&x8[0] = *(const float4*)(xp + ks * 32);
                *(float4*)&x8[4] = *(const float4*)(xp + ks * 32 + 4);
            } else {
#pragma unroll
                for (int i = 0; i < 8; ++i) x8[i] = 0.f;
            }
            split8(x8, ahx[ks], alx[ks]);
        }
    }

    for (int r = 0; r < R; ++r) {
        const short* PH = Phi + (size_t)(r * PREL) * PFRAG;
        const short* PL = Plo + (size_t)(r * PREL) * PFRAG;
        const float* b1r = b1 + r * H;
        const float* b2r = b2 + r * H;
        const float* b3r = b3 + r * D;

        // layer 1: X(16x128) @ W1(128x64) — A from registers
        f32x4 acc[8];
#pragma unroll
        for (int n = 0; n < 4; ++n) acc[n] = (f32x4){0.f, 0.f, 0.f, 0.f};
        mfma_layer_regA<4, 4>(ahx, alx, PH, PL, lane, acc);
        store_C_lds<4>(acc, b1r, &Hs[m16 * LDH], LDH, lane);   // H1

        // layer 2: H1(16x64) @ W2(64x64) -> H2 (in place)
#pragma unroll
        for (int n = 0; n < 4; ++n) acc[n] = (f32x4){0.f, 0.f, 0.f, 0.f};
        mfma_layer<4, 2>(&Hs[m16 * LDH], LDH, PH + (size_t)16 * PFRAG, PL + (size_t)16 * PFRAG, lane, acc);
        store_C_lds<4>(acc, b2r, &Hs[m16 * LDH], LDH, lane);   // H2

        // layer 3: H2(16x64) @ W3(64x128), relu -> T strip
#pragma unroll
        for (int n = 0; n < 8; ++n) acc[n] = (f32x4){0.f, 0.f, 0.f, 0.f};
        mfma_layer<8, 2>(&Hs[m16 * LDH], LDH, PH + (size_t)24 * PFRAG, PL + (size_t)24 * PFRAG, lane, acc);
        store_C_lds<8>(acc, b3r, &Ts[m16 * LDC], LDC, lane);   // T

        // U projection: T(16x128) @ Wu1_{r+1}(128x64)
#pragma unroll
        for (int n = 0; n < 4; ++n) acc[n] = (f32x4){0.f, 0.f, 0.f, 0.f};
        mfma_layer<4, 4>(&Ts[m16 * LDC], LDC, PH + (size_t)40 * PFRAG, PL + (size_t)40 * PFRAG, lane, acc);
        {
            int r0 = (lane >> 4) << 2;
#pragma unroll
            for (int n = 0; n < 4; ++n) {
                int col = n * 16 + (lane & 15);
#pragma unroll
                for (int q = 0; q < 4; ++q) {
                    int node = n0 + m16 + r0 + q;
                    if (node < N)
                        U[((size_t)node * R + r) * H + col] = acc[n][q];
                }
            }
        }
    }
}

// ---------------- Stage B: gather S[n] = sum over in-edges of U[src*4+rel] ----------------

__global__ __launch_bounds__(256) void k_gather(
    const float* __restrict__ U,
    const int* __restrict__ cnt, const int* __restrict__ offs, const int* __restrict__ eidx,
    float* __restrict__ S, int N)
{
    const int wid = threadIdx.x >> 6, lane = threadIdx.x & 63;
    const int n = blockIdx.x * 4 + wid;
    if (n >= N) return;
    const int g = cnt[n];
    const int s = offs[n];
    float acc = 0.f;
    for (int base = 0; base < g; base += 64) {
        int m = g - base; if (m > 64) m = 64;
        int v = 0;
        if (lane < m) v = eidx[s + base + lane];
        for (int j0 = 0; j0 < m; j0 += 8) {
            int lim = m - j0; if (lim > 8) lim = 8;
            float t[8];
#pragma unroll
            for (int j = 0; j < 8; ++j) {
                int vi = __shfl(v, j0 + j);
                t[j] = (j < lim) ? U[(size_t)vi * H + lane] : 0.f;
            }
#pragma unroll
            for (int j = 0; j < 8; ++j) acc += t[j];
        }
    }
    S[(size_t)n * H + lane] = acc;
}

// ---------------- Stage C: updater MLP + select (split-bf16 MFMA, barrier-free) ----------------
// chunk0 A-fragments loaded direct from global into registers; LDS = Hs only.

__global__ __launch_bounds__(256) void k_upd(
    const float* __restrict__ X, const float* __restrict__ S,
    const int* __restrict__ cnt, const int* __restrict__ node_type,
    const short* __restrict__ Phi, const short* __restrict__ Plo,
    const float* __restrict__ bu1, const float* __restrict__ bu2, const float* __restrict__ bu3,
    float* __restrict__ out, int N)
{
    __shared__ float Hs[NT * LDH];   // H1 / H2 strips (per wave)

    const int tid = threadIdx.x;
    const int lane = tid & 63;
    const int w = tid >> 6;
    const int m16 = w * 16;
    const int n0 = blockIdx.x * NT;

    const short* PH = Phi + (size_t)UBASE * PFRAG;
    const short* PL = Plo + (size_t)UBASE * PFRAG;

    // stage chunk0 = relu(x) * (indeg > 0) direct into register A-fragments
    bf16x8 ahx[4], alx[4];
    {
        int row = n0 + m16 + (lane & 15);
        bool ok = (row < N) && (cnt[row] > 0);
        const float* xp = X + (size_t)row * D + ((lane >> 4) << 3);
#pragma unroll
        for (int ks = 0; ks < 4; ++ks) {
            float x8[8];
            if (ok) {
                float4 a = *(const float4*)(xp + ks * 32);
                float4 b = *(const float4*)(xp + ks * 32 + 4);
                a = relu4(a); b = relu4(b);
                *(float4*)&x8[0] = a;
                *(float4*)&x8[4] = b;
            } else {
#pragma unroll
                for (int i = 0; i < 8; ++i) x8[i] = 0.f;
            }
            split8(x8, ahx[ks], alx[ks]);
        }
    }

    // layer 1: chunk0 @ Wu1[0:128] + S + bu1, relu -> H1
    f32x4 acc[8];
#pragma unroll
    for (int n = 0; n < 4; ++n) acc[n] = (f32x4){0.f, 0.f, 0.f, 0.f};
    mfma_layer_regA<4, 4>(ahx, alx, PH, PL, lane, acc);
    {
        int r0 = (lane >> 4) << 2;
#pragma unroll
        for (int n = 0; n < 4; ++n) {
            int col = n * 16 + (lane & 15);
            float bv = bu1[col];
#pragma unroll
            for (int q = 0; q < 4; ++q) {
                int node = n0 + m16 + r0 + q;
                float sv = (node < N) ? S[(size_t)node * H + col] : 0.f;
                Hs[(m16 + r0 + q) * LDH + col] = fmaxf(acc[n][q] + bv + sv, 0.f);
            }
        }
    }

    // layer 2: H1 @ Wu2, relu -> H2 (in place)
#pragma unroll
    for (int n = 0; n < 4; ++n) acc[n] = (f32x4){0.f, 0.f, 0.f, 0.f};
    mfma_layer<4, 2>(&Hs[m16 * LDH], LDH, PH + (size_t)16 * PFRAG, PL + (size_t)16 * PFRAG, lane, acc);
    store_C_lds<4>(acc, bu2, &Hs[m16 * LDH], LDH, lane);

    // layer 3: H2 @ Wu3 (linear) + select by node_type
#pragma unroll
    for (int n = 0; n < 8; ++n) acc[n] = (f32x4){0.f, 0.f, 0.f, 0.f};
    mfma_layer<8, 2>(&Hs[m16 * LDH], LDH, PH + (size_t)24 * PFRAG, PL + (size_t)24 * PFRAG, lane, acc);
    {
        int r0 = (lane >> 4) << 2;
#pragma unroll
        for (int q = 0; q < 4; ++q) {
            int node = n0 + m16 + r0 + q;
            if (node >= N) continue;
            int t = node_type[node];
#pragma unroll
            for (int n = 0; n < 8; ++n) {
                int col = n * 16 + (lane & 15);
                float o = (t <= 1) ? (acc[n][q] + bu3[col])
                                   : X[(size_t)node * D + col];
                out[(size_t)node * D + col] = o;
            }
        }
    }
}

extern "C" void kernel_launch(void* const* d_in, const int* in_sizes, int n_in,
                              void* d_out, int out_size, void* d_ws, size_t ws_size,
                              hipStream_t stream) {
    const float* X     = (const float*)d_in[0];
    const int*   src   = (const int*)d_in[1];
    const int*   dst   = (const int*)d_in[2];
    const int*   etype = (const int*)d_in[3];
    const int*   ntype = (const int*)d_in[4];
    const float* W1    = (const float*)d_in[5];
    const float* b1    = (const float*)d_in[6];
    const float* W2    = (const float*)d_in[7];
    const float* b2    = (const float*)d_in[8];
    const float* W3    = (const float*)d_in[9];
    const float* b3    = (const float*)d_in[10];
    const float* Wu1   = (const float*)d_in[11];
    const float* bu1   = (const float*)d_in[12];
    const float* Wu2   = (const float*)d_in[13];
    const float* bu2   = (const float*)d_in[14];
    const float* Wu3   = (const float*)d_in[15];
    const float* bu3   = (const float*)d_in[16];
    float* out = (float*)d_out;

    const int N = in_sizes[4];
    const int E = in_sizes[1];

    // workspace layout
    float* U    = (float*)d_ws;                       // N*R*H floats (51.2 MB)
    float* S    = U + (size_t)N * R * H;              // N*H floats (12.8 MB)
    int* cnt    = (int*)(S + (size_t)N * H);          // N
    int* offs   = cnt + N;                            // N
    int* cursor = offs + N;                           // N
    int* eidx   = cursor + N;                         // E
    short* Phi  = (short*)(eidx + E);                 // NFRAG*PFRAG shorts
    short* Plo  = Phi + (size_t)NFRAG * PFRAG;
    int* bsum   = (int*)(Plo + (size_t)NFRAG * PFRAG);  // ceil(N/256)

    hipMemsetAsync(cnt, 0, (size_t)N * sizeof(int), stream);

    int eb = (E + 255) / 256;
    int G = (N + 255) / 256;
    k_count<<<eb, 256, 0, stream>>>(dst, cnt, E);
    k_blocksum<<<G, 256, 0, stream>>>(cnt, bsum, N);
    k_scan_bsums<<<1, 1024, 0, stream>>>(bsum, G);
    k_scan_offs<<<G, 256, 0, stream>>>(cnt, bsum, offs, cursor, N);
    k_fill<<<eb, 256, 0, stream>>>(src, dst, etype, cursor, eidx, E);
    k_wprep<<<19, 256, 0, stream>>>(W1, W2, W3, Wu1, Wu2, Wu3, Phi, Plo);

    int tiles = (N + NT - 1) / NT;
    k_mlp_rel<<<tiles, 256, 0, stream>>>(X, b1, b2, b3, Phi, Plo, U, N);
    k_gather<<<(N + 3) / 4, 256, 0, stream>>>(U, cnt, offs, eidx, S, N);
    k_upd<<<tiles, 256, 0, stream>>>(X, S, cnt, ntype, Phi, Plo, bu1, bu2, bu3, out, N);
}

// Round 9
// 231.307 us; speedup vs baseline: 1.1301x; 1.0873x over previous
//
#include <hip/hip_runtime.h>
#include <hip/hip_bf16.h>

// Problem constants (static per reference)
#define D 128
#define H 64
#define R 4
#define NT 64      // nodes per tile/block (4 waves x 16 rows)
#define LDC 132    // LDS stride (floats) for the per-wave strip

// MFMA fragment types
typedef __attribute__((ext_vector_type(8))) short bf16x8;
typedef __attribute__((ext_vector_type(4))) float f32x4;

// Weight-prep layout: per relation, 56 frags of 512 bf16 elems (64 lanes x 8):
//   W1 frags [0,16), W2 [16,24), W3 [24,40), Wu1_{r+1} [40,56)
// Updater block appended at UBASE: Wu1[0:128] [0,16), Wu2 [16,24), Wu3 [24,40)
// Frag f = ntile*KSTEPS + kstep; lane l covers col = ntile*16+(l&15),
// k = kstep*32 + (l>>4)*8 + i.  (Same phi used for A -> phi cancels.)
#define PREL 56
#define PFRAG 512
#define UBASE (R * PREL)     // 224
#define UPREL 40
#define NFRAG (UBASE + UPREL)

__device__ __forceinline__ float4 relu4(float4 v) {
    return make_float4(fmaxf(v.x, 0.f), fmaxf(v.y, 0.f), fmaxf(v.z, 0.f), fmaxf(v.w, 0.f));
}

// split fp32 -> bf16 hi (RTZ) + bf16 lo (residual, RTZ)
__device__ __forceinline__ void split1(float x, short& hi, short& lo) {
    unsigned u = __float_as_uint(x);
    unsigned hb = u & 0xffff0000u;
    float res = x - __uint_as_float(hb);
    hi = (short)(u >> 16);
    lo = (short)(__float_as_uint(res) >> 16);
}

__device__ __forceinline__ void split8(const float* x8, bf16x8& hi, bf16x8& lo) {
#pragma unroll
    for (int i = 0; i < 8; ++i) {
        short h, l;
        split1(x8[i], h, l);
        hi[i] = h; lo[i] = l;
    }
}

// A from LDS fp32 (split on the fly), B pre-split global.
template<int NT_TILES, int KSTEPS>
__device__ __forceinline__ void mfma_layer(const float* Als, int ld,
                                           const short* __restrict__ Bhi,
                                           const short* __restrict__ Blo,
                                           int lane, f32x4* acc) {
#pragma unroll
    for (int ks = 0; ks < KSTEPS; ++ks) {
        const float* ap = Als + (lane & 15) * ld + ks * 32 + ((lane >> 4) << 3);
        float x8[8];
        *(float4*)&x8[0] = *(const float4*)ap;
        *(float4*)&x8[4] = *(const float4*)(ap + 4);
        bf16x8 ah, al;
        split8(x8, ah, al);
#pragma unroll
        for (int n = 0; n < NT_TILES; ++n) {
            int f = n * KSTEPS + ks;
            bf16x8 bh = *(const bf16x8*)(Bhi + (((size_t)f * 64 + lane) << 3));
            bf16x8 bl = *(const bf16x8*)(Blo + (((size_t)f * 64 + lane) << 3));
            acc[n] = __builtin_amdgcn_mfma_f32_16x16x32_bf16(ah, bh, acc[n], 0, 0, 0);
            acc[n] = __builtin_amdgcn_mfma_f32_16x16x32_bf16(ah, bl, acc[n], 0, 0, 0);
            acc[n] = __builtin_amdgcn_mfma_f32_16x16x32_bf16(al, bh, acc[n], 0, 0, 0);
        }
    }
}

// A from pre-split registers, B pre-split global.
template<int NT_TILES, int KSTEPS>
__device__ __forceinline__ void mfma_layer_regA(const bf16x8* ah, const bf16x8* al,
                                                const short* __restrict__ Bhi,
                                                const short* __restrict__ Blo,
                                                int lane, f32x4* acc) {
#pragma unroll
    for (int ks = 0; ks < KSTEPS; ++ks) {
#pragma unroll
        for (int n = 0; n < NT_TILES; ++n) {
            int f = n * KSTEPS + ks;
            bf16x8 bh = *(const bf16x8*)(Bhi + (((size_t)f * 64 + lane) << 3));
            bf16x8 bl = *(const bf16x8*)(Blo + (((size_t)f * 64 + lane) << 3));
            acc[n] = __builtin_amdgcn_mfma_f32_16x16x32_bf16(ah[ks], bh, acc[n], 0, 0, 0);
            acc[n] = __builtin_amdgcn_mfma_f32_16x16x32_bf16(ah[ks], bl, acc[n], 0, 0, 0);
            acc[n] = __builtin_amdgcn_mfma_f32_16x16x32_bf16(al[ks], bh, acc[n], 0, 0, 0);
        }
    }
}

// bias + relu + store C strip to LDS fp32 (C/D layout: col=lane&15, row=(lane>>4)*4+reg)
template<int NT_TILES>
__device__ __forceinline__ void store_C_lds(const f32x4* acc, const float* __restrict__ bias,
                                            float* Ld, int ld, int lane) {
    int r0 = (lane >> 4) << 2;
#pragma unroll
    for (int n = 0; n < NT_TILES; ++n) {
        int col = n * 16 + (lane & 15);
        float bv = bias[col];
#pragma unroll
        for (int q = 0; q < 4; ++q)
            Ld[(r0 + q) * ld + col] = fmaxf(acc[n][q] + bv, 0.f);
    }
}

// ---------------- CSR build ----------------

__global__ __launch_bounds__(256) void k_count(const int* __restrict__ dst, int* __restrict__ cnt, int E) {
    int e = blockIdx.x * 256 + threadIdx.x;
    if (e < E) atomicAdd(&cnt[dst[e]], 1);
}

__global__ __launch_bounds__(256) void k_blocksum(const int* __restrict__ cnt,
                                                  int* __restrict__ bsum, int N) {
    __shared__ int red[256];
    int i = blockIdx.x * 256 + threadIdx.x;
    red[threadIdx.x] = (i < N) ? cnt[i] : 0;
    __syncthreads();
    for (int off = 128; off > 0; off >>= 1) {
        if (threadIdx.x < off) red[threadIdx.x] += red[threadIdx.x + off];
        __syncthreads();
    }
    if (threadIdx.x == 0) bsum[blockIdx.x] = red[0];
}

__global__ __launch_bounds__(1024) void k_scan_bsums(int* __restrict__ bsum, int G) {
    __shared__ int s[1024];
    int t = threadIdx.x;
    int v = (t < G) ? bsum[t] : 0;
    s[t] = v;
    __syncthreads();
    for (int off = 1; off < 1024; off <<= 1) {
        int u = (t >= off) ? s[t - off] : 0;
        __syncthreads();
        s[t] += u;
        __syncthreads();
    }
    if (t < G) bsum[t] = s[t] - v;   // exclusive
}

__global__ __launch_bounds__(256) void k_scan_offs(const int* __restrict__ cnt,
                                                   const int* __restrict__ bsum,
                                                   int* __restrict__ offs,
                                                   int* __restrict__ cursor, int N) {
    __shared__ int s[256];
    int t = threadIdx.x;
    int i = blockIdx.x * 256 + t;
    int v = (i < N) ? cnt[i] : 0;
    s[t] = v;
    __syncthreads();
    for (int off = 1; off < 256; off <<= 1) {
        int u = (t >= off) ? s[t - off] : 0;
        __syncthreads();
        s[t] += u;
        __syncthreads();
    }
    if (i < N) {
        int e = s[t] - v + bsum[blockIdx.x];
        offs[i] = e;
        cursor[i] = e;
    }
}

__global__ __launch_bounds__(256) void k_fill(const int* __restrict__ src, const int* __restrict__ dst,
                                              const int* __restrict__ etype, int* __restrict__ cursor,
                                              int* __restrict__ eidx, int E) {
    int e = blockIdx.x * 256 + threadIdx.x;
    if (e < E) {
        int d = dst[e];
        int p = atomicAdd(&cursor[d], 1);
        eidx[p] = src[e] * 4 + etype[e];
    }
}

// ---------------- Weight prep: split + frag-swizzle all B matrices ----------------

__global__ __launch_bounds__(256) void k_wprep(
    const float* __restrict__ W1, const float* __restrict__ W2,
    const float* __restrict__ W3, const float* __restrict__ Wu1,
    const float* __restrict__ Wu2, const float* __restrict__ Wu3,
    short* __restrict__ Phi, short* __restrict__ Plo)
{
    int pair = blockIdx.x;
    const float* src; int KS, NTl, fragbase, ncol;
    if (pair < 16) {
        int r = pair >> 2, mat = pair & 3;
        if (mat == 0)      { src = W1  + (size_t)r * (D * H);       KS = 4; NTl = 4; fragbase = r * PREL + 0;  ncol = 64;  }
        else if (mat == 1) { src = W2  + (size_t)r * (H * H);       KS = 2; NTl = 4; fragbase = r * PREL + 16; ncol = 64;  }
        else if (mat == 2) { src = W3  + (size_t)r * (H * D);       KS = 2; NTl = 8; fragbase = r * PREL + 24; ncol = 128; }
        else               { src = Wu1 + (size_t)(r + 1) * D * H;   KS = 4; NTl = 4; fragbase = r * PREL + 40; ncol = 64;  }
    } else {
        int mat = pair - 16;
        if (mat == 0)      { src = Wu1; KS = 4; NTl = 4; fragbase = UBASE + 0;  ncol = 64;  }  // rows 0..127
        else if (mat == 1) { src = Wu2; KS = 2; NTl = 4; fragbase = UBASE + 16; ncol = 64;  }
        else               { src = Wu3; KS = 2; NTl = 8; fragbase = UBASE + 24; ncol = 128; }
    }
    int nf = NTl * KS;
    for (int u = threadIdx.x; u < nf * 64; u += 256) {
        int f = u >> 6, lane = u & 63;
        int n = f / KS, ks = f - n * KS;
        int col = n * 16 + (lane & 15);
        int k0 = ks * 32 + ((lane >> 4) << 3);
        size_t dstp = (((size_t)(fragbase + f)) * 64 + (size_t)lane) * 8;
#pragma unroll
        for (int i = 0; i < 8; ++i) {
            short h, l;
            split1(src[(size_t)(k0 + i) * ncol + col], h, l);
            Phi[dstp + i] = h;
            Plo[dstp + i] = l;
        }
    }
}

// ---------------- Stage A: per-(tile, relation) message MLP + Wu1 fold ----------------
// One block per (64-node tile, relation). Each wave owns 16 rows: X staged
// direct from global into register A-fragments (split once); H1/H2/T share a
// single per-wave 16x132 LDS strip (all phases stride LDC; in-place reuse is
// wave-private, compiler orders aliasing ds ops). Barrier-free. 33792 B LDS
// => 4 blocks/CU.

__global__ __launch_bounds__(256) void k_mlp_rel(
    const float* __restrict__ X,
    const float* __restrict__ b1, const float* __restrict__ b2, const float* __restrict__ b3,
    const short* __restrict__ Phi, const short* __restrict__ Plo,
    float* __restrict__ U, int N)
{
    __shared__ float Bsh[NT * LDC];   // per-wave 16-row strips

    const int tid = threadIdx.x;
    const int lane = tid & 63;
    const int w = tid >> 6;
    const int m16 = w * 16;
    const int r = blockIdx.x & 3;
    const int n0 = (blockIdx.x >> 2) * NT;

    const short* PH = Phi + (size_t)(r * PREL) * PFRAG;
    const short* PL = Plo + (size_t)(r * PREL) * PFRAG;
    const float* b1r = b1 + r * H;
    const float* b2r = b2 + r * H;
    const float* b3r = b3 + r * D;

    float* Ws = &Bsh[m16 * LDC];   // this wave's strip

    // stage X A-fragments direct from global into registers, split once
    bf16x8 ahx[4], alx[4];
    {
        int row = n0 + m16 + (lane & 15);
        const float* xp = X + (size_t)row * D + ((lane >> 4) << 3);
        bool ok = (row < N);
#pragma unroll
        for (int ks = 0; ks < 4; ++ks) {
            float x8[8];
            if (ok) {
                *(float4*)&x8[0] = *(const float4*)(xp + ks * 32);
                *(float4*)&x8[4] = *(const float4*)(xp + ks * 32 + 4);
            } else {
#pragma unroll
                for (int i = 0; i < 8; ++i) x8[i] = 0.f;
            }
            split8(x8, ahx[ks], alx[ks]);
        }
    }

    // layer 1: X(16x128) @ W1(128x64) — A from registers
    f32x4 acc[8];
#pragma unroll
    for (int n = 0; n < 4; ++n) acc[n] = (f32x4){0.f, 0.f, 0.f, 0.f};
    mfma_layer_regA<4, 4>(ahx, alx, PH, PL, lane, acc);
    store_C_lds<4>(acc, b1r, Ws, LDC, lane);   // H1 in cols 0:63

    // layer 2: H1(16x64) @ W2(64x64) -> H2 (in place, cols 0:63)
#pragma unroll
    for (int n = 0; n < 4; ++n) acc[n] = (f32x4){0.f, 0.f, 0.f, 0.f};
    mfma_layer<4, 2>(Ws, LDC, PH + (size_t)16 * PFRAG, PL + (size_t)16 * PFRAG, lane, acc);
    store_C_lds<4>(acc, b2r, Ws, LDC, lane);   // H2

    // layer 3: H2(16x64) @ W3(64x128), relu -> T (cols 0:127, same strip)
#pragma unroll
    for (int n = 0; n < 8; ++n) acc[n] = (f32x4){0.f, 0.f, 0.f, 0.f};
    mfma_layer<8, 2>(Ws, LDC, PH + (size_t)24 * PFRAG, PL + (size_t)24 * PFRAG, lane, acc);
    store_C_lds<8>(acc, b3r, Ws, LDC, lane);   // T

    // U projection: T(16x128) @ Wu1_{r+1}(128x64)
#pragma unroll
    for (int n = 0; n < 4; ++n) acc[n] = (f32x4){0.f, 0.f, 0.f, 0.f};
    mfma_layer<4, 4>(Ws, LDC, PH + (size_t)40 * PFRAG, PL + (size_t)40 * PFRAG, lane, acc);
    {
        int r0 = (lane >> 4) << 2;
#pragma unroll
        for (int n = 0; n < 4; ++n) {
            int col = n * 16 + (lane & 15);
#pragma unroll
            for (int q = 0; q < 4; ++q) {
                int node = n0 + m16 + r0 + q;
                if (node < N)
                    U[((size_t)node * R + r) * H + col] = acc[n][q];
            }
        }
    }
}

// ---------------- Stage B: gather S[n] = sum over in-edges of U[src*4+rel] ----------------

__global__ __launch_bounds__(256) void k_gather(
    const float* __restrict__ U,
    const int* __restrict__ cnt, const int* __restrict__ offs, const int* __restrict__ eidx,
    float* __restrict__ S, int N)
{
    const int wid = threadIdx.x >> 6, lane = threadIdx.x & 63;
    const int n = blockIdx.x * 4 + wid;
    if (n >= N) return;
    const int g = cnt[n];
    const int s = offs[n];
    float acc = 0.f;
    for (int base = 0; base < g; base += 64) {
        int m = g - base; if (m > 64) m = 64;
        int v = 0;
        if (lane < m) v = eidx[s + base + lane];
        for (int j0 = 0; j0 < m; j0 += 8) {
            int lim = m - j0; if (lim > 8) lim = 8;
            float t[8];
#pragma unroll
            for (int j = 0; j < 8; ++j) {
                int vi = __shfl(v, j0 + j);
                t[j] = (j < lim) ? U[(size_t)vi * H + lane] : 0.f;
            }
#pragma unroll
            for (int j = 0; j < 8; ++j) acc += t[j];
        }
    }
    S[(size_t)n * H + lane] = acc;
}

// ---------------- Stage C: updater MLP + select (split-bf16 MFMA, barrier-free) ----------------

__global__ __launch_bounds__(256) void k_upd(
    const float* __restrict__ X, const float* __restrict__ S,
    const int* __restrict__ cnt, const int* __restrict__ node_type,
    const short* __restrict__ Phi, const short* __restrict__ Plo,
    const float* __restrict__ bu1, const float* __restrict__ bu2, const float* __restrict__ bu3,
    float* __restrict__ out, int N)
{
    __shared__ float Hsh[NT * LDC];   // per-wave strips (H1/H2)

    const int tid = threadIdx.x;
    const int lane = tid & 63;
    const int w = tid >> 6;
    const int m16 = w * 16;
    const int n0 = blockIdx.x * NT;

    const short* PH = Phi + (size_t)UBASE * PFRAG;
    const short* PL = Plo + (size_t)UBASE * PFRAG;

    float* Ws = &Hsh[m16 * LDC];

    // stage chunk0 = relu(x) * (indeg > 0) direct into register A-fragments
    bf16x8 ahx[4], alx[4];
    {
        int row = n0 + m16 + (lane & 15);
        bool ok = (row < N) && (cnt[row] > 0);
        const float* xp = X + (size_t)row * D + ((lane >> 4) << 3);
#pragma unroll
        for (int ks = 0; ks < 4; ++ks) {
            float x8[8];
            if (ok) {
                float4 a = *(const float4*)(xp + ks * 32);
                float4 b = *(const float4*)(xp + ks * 32 + 4);
                a = relu4(a); b = relu4(b);
                *(float4*)&x8[0] = a;
                *(float4*)&x8[4] = b;
            } else {
#pragma unroll
                for (int i = 0; i < 8; ++i) x8[i] = 0.f;
            }
            split8(x8, ahx[ks], alx[ks]);
        }
    }

    // layer 1: chunk0 @ Wu1[0:128] + S + bu1, relu -> H1
    f32x4 acc[8];
#pragma unroll
    for (int n = 0; n < 4; ++n) acc[n] = (f32x4){0.f, 0.f, 0.f, 0.f};
    mfma_layer_regA<4, 4>(ahx, alx, PH, PL, lane, acc);
    {
        int r0 = (lane >> 4) << 2;
#pragma unroll
        for (int n = 0; n < 4; ++n) {
            int col = n * 16 + (lane & 15);
            float bv = bu1[col];
#pragma unroll
            for (int q = 0; q < 4; ++q) {
                int node = n0 + m16 + r0 + q;
                float sv = (node < N) ? S[(size_t)node * H + col] : 0.f;
                Ws[(r0 + q) * LDC + col] = fmaxf(acc[n][q] + bv + sv, 0.f);
            }
        }
    }

    // layer 2: H1 @ Wu2, relu -> H2 (in place)
#pragma unroll
    for (int n = 0; n < 4; ++n) acc[n] = (f32x4){0.f, 0.f, 0.f, 0.f};
    mfma_layer<4, 2>(Ws, LDC, PH + (size_t)16 * PFRAG, PL + (size_t)16 * PFRAG, lane, acc);
    store_C_lds<4>(acc, bu2, Ws, LDC, lane);

    // layer 3: H2 @ Wu3 (linear) + select by node_type
#pragma unroll
    for (int n = 0; n < 8; ++n) acc[n] = (f32x4){0.f, 0.f, 0.f, 0.f};
    mfma_layer<8, 2>(Ws, LDC, PH + (size_t)24 * PFRAG, PL + (size_t)24 * PFRAG, lane, acc);
    {
        int r0 = (lane >> 4) << 2;
#pragma unroll
        for (int q = 0; q < 4; ++q) {
            int node = n0 + m16 + r0 + q;
            if (node >= N) continue;
            int t = node_type[node];
#pragma unroll
            for (int n = 0; n < 8; ++n) {
                int col = n * 16 + (lane & 15);
                float o = (t <= 1) ? (acc[n][q] + bu3[col])
                                   : X[(size_t)node * D + col];
                out[(size_t)node * D + col] = o;
            }
        }
    }
}

extern "C" void kernel_launch(void* const* d_in, const int* in_sizes, int n_in,
                              void* d_out, int out_size, void* d_ws, size_t ws_size,
                              hipStream_t stream) {
    const float* X     = (const float*)d_in[0];
    const int*   src   = (const int*)d_in[1];
    const int*   dst   = (const int*)d_in[2];
    const int*   etype = (const int*)d_in[3];
    const int*   ntype = (const int*)d_in[4];
    const float* W1    = (const float*)d_in[5];
    const float* b1    = (const float*)d_in[6];
    const float* W2    = (const float*)d_in[7];
    const float* b2    = (const float*)d_in[8];
    const float* W3    = (const float*)d_in[9];
    const float* b3    = (const float*)d_in[10];
    const float* Wu1   = (const float*)d_in[11];
    const float* bu1   = (const float*)d_in[12];
    const float* Wu2   = (const float*)d_in[13];
    const float* bu2   = (const float*)d_in[14];
    const float* Wu3   = (const float*)d_in[15];
    const float* bu3   = (const float*)d_in[16];
    float* out = (float*)d_out;

    const int N = in_sizes[4];
    const int E = in_sizes[1];

    // workspace layout
    float* U    = (float*)d_ws;                       // N*R*H floats (51.2 MB)
    float* S    = U + (size_t)N * R * H;              // N*H floats (12.8 MB)
    int* cnt    = (int*)(S + (size_t)N * H);          // N
    int* offs   = cnt + N;                            // N
    int* cursor = offs + N;                           // N
    int* eidx   = cursor + N;                         // E
    short* Phi  = (short*)(eidx + E);                 // NFRAG*PFRAG shorts
    short* Plo  = Phi + (size_t)NFRAG * PFRAG;
    int* bsum   = (int*)(Plo + (size_t)NFRAG * PFRAG);  // ceil(N/256)

    hipMemsetAsync(cnt, 0, (size_t)N * sizeof(int), stream);

    int eb = (E + 255) / 256;
    int G = (N + 255) / 256;
    k_count<<<eb, 256, 0, stream>>>(dst, cnt, E);
    k_blocksum<<<G, 256, 0, stream>>>(cnt, bsum, N);
    k_scan_bsums<<<1, 1024, 0, stream>>>(bsum, G);
    k_scan_offs<<<G, 256, 0, stream>>>(cnt, bsum, offs, cursor, N);
    k_fill<<<eb, 256, 0, stream>>>(src, dst, etype, cursor, eidx, E);
    k_wprep<<<19, 256, 0, stream>>>(W1, W2, W3, Wu1, Wu2, Wu3, Phi, Plo);

    int tiles = (N + NT - 1) / NT;
    k_mlp_rel<<<tiles * R, 256, 0, stream>>>(X, b1, b2, b3, Phi, Plo, U, N);
    k_gather<<<(N + 3) / 4, 256, 0, stream>>>(U, cnt, offs, eidx, S, N);
    k_upd<<<tiles, 256, 0, stream>>>(X, S, cnt, ntype, Phi, Plo, bu1, bu2, bu3, out, N);
}